// Round 6
// baseline (1699.372 us; speedup 1.0000x reference)
//
#include <hip/hip_runtime.h>

#define NF 256        // features
#define NT 4096       // time steps
#define NB 64         // batch
#define CHUNKS 16     // time chunks per batch
#define TPC (NT / CHUNKS)   // 256 rows per chunk
#define NWG (NB * CHUNKS)   // 1024 blocks
#define EPS 1e-5f

typedef float vfloat4 __attribute__((ext_vector_type(4)));

__device__ __forceinline__ float fast_tanh(float v) {
    float e = __expf(2.0f * v);                        // inf/0 endpoints -> +-1
    return 1.0f - 2.0f * __builtin_amdgcn_rcpf(e + 1.0f);
}

// ---------------------------------------------------------------------------
// One persistent kernel: reduce own slice -> last-arriver per batch does
// stats+MLP -> all blocks spin on flag -> apply own slice.
// __launch_bounds__(256,4): 4 waves/SIMD -> 4 blocks/CU -> all 1024 blocks
// co-resident on 256 CUs, so spin-wait can never starve a producer.
// ---------------------------------------------------------------------------
__global__ __launch_bounds__(256, 4) void k_fused(
    const float* __restrict__ x,
    const float* __restrict__ W1, const float* __restrict__ b1,
    const float* __restrict__ W2, const float* __restrict__ b2,
    const float4* __restrict__ gamma, const float4* __restrict__ beta,
    float* __restrict__ partial, float* __restrict__ sA, float* __restrict__ cA,
    int* __restrict__ cnt, int* __restrict__ flag,
    float4* __restrict__ out)
{
    const int blk = blockIdx.x;
    const int b   = blk >> 4;            // batch
    const int c   = blk & 15;            // chunk
    const int tid = threadIdx.x;
    const int q   = tid & 63;            // float4 slot within a feature row
    const int g   = tid >> 6;            // row group 0..3

    // ---- phase 1: partial sum / sumsq over this chunk's 256 rows ----------
    const float4* __restrict__ xrow =
        (const float4*)(x + ((size_t)b * NT + (size_t)c * TPC) * NF);

    float4 s  = {0.f, 0.f, 0.f, 0.f};
    float4 ss = {0.f, 0.f, 0.f, 0.f};
    #pragma unroll 8
    for (int t = g; t < TPC; t += 4) {
        float4 v = xrow[t * (NF / 4) + q];
        s.x += v.x; s.y += v.y; s.z += v.z; s.w += v.w;
        ss.x = fmaf(v.x, v.x, ss.x);
        ss.y = fmaf(v.y, v.y, ss.y);
        ss.z = fmaf(v.z, v.z, ss.z);
        ss.w = fmaf(v.w, v.w, ss.w);
    }

    __shared__ float4 smS[4][64];
    __shared__ float4 smQ[4][64];
    smS[g][q] = s;
    smQ[g][q] = ss;
    __syncthreads();

    const float* sS = (const float*)smS;
    const float* sQ = (const float*)smQ;
    float sum = sS[0 * NF + tid] + sS[1 * NF + tid] + sS[2 * NF + tid] + sS[3 * NF + tid];
    float sq  = sQ[0 * NF + tid] + sQ[1 * NF + tid] + sQ[2 * NF + tid] + sQ[3 * NF + tid];

    float* p = partial + (size_t)blk * 2 * NF;
    p[tid]      = sum;
    p[NF + tid] = sq;
    __threadfence();                     // make partials device-visible
    __syncthreads();

    __shared__ int isLast;
    if (tid == 0) {
        int old = atomicAdd(&cnt[b], 1); // device-scope RMW
        isLast = (old == CHUNKS - 1);
    }
    __syncthreads();

    // ---- phase 2 (one block per batch): stats + MLP + fold constants ------
    if (isLast) {
        __threadfence();                 // acquire side for partial reads
        const int f = tid;
        float tsum = 0.f, tsq = 0.f;
        #pragma unroll
        for (int cc = 0; cc < CHUNKS; ++cc) {
            const float* pp = partial + (size_t)(b * CHUNKS + cc) * 2 * NF;
            tsum += pp[f];
            tsq  += pp[NF + f];
        }
        const float mean = tsum * (1.0f / NT);
        float var = fmaxf(tsq * (1.0f / NT) - mean * mean, 0.0f);
        const float stdv = sqrtf(var + EPS);

        __shared__ float stats[2 * NF];
        __shared__ float h[NF];
        stats[f]      = mean;
        stats[NF + f] = stdv;
        __syncthreads();

        float acc = b1[f];
        const float* w1r = W1 + (size_t)f * (2 * NF);
        #pragma unroll 8
        for (int k = 0; k < 2 * NF; ++k) acc = fmaf(stats[k], w1r[k], acc);
        h[f] = fmaxf(acc, 0.0f);
        __syncthreads();

        float acc2 = b2[f];
        const float* w2r = W2 + (size_t)f * NF;
        #pragma unroll 8
        for (int k = 0; k < NF; ++k) acc2 = fmaf(h[k], w2r[k], acc2);
        const float alpha = 1.0f / (1.0f + __expf(-acc2));

        const float sv = alpha / stdv;
        sA[b * NF + f] = sv;             // scale
        cA[b * NF + f] = -mean * sv;     // offset
        __threadfence();
        __syncthreads();
        if (tid == 0)
            __hip_atomic_store(&flag[b], 1, __ATOMIC_RELEASE, __HIP_MEMORY_SCOPE_AGENT);
    }

    // ---- wait for this batch's constants -----------------------------------
    if (tid == 0) {
        while (__hip_atomic_load(&flag[b], __ATOMIC_ACQUIRE, __HIP_MEMORY_SCOPE_AGENT) == 0) {
            __builtin_amdgcn_s_sleep(16);
        }
    }
    __syncthreads();

    // ---- phase 3: apply on own slice (same 256 KB this block just read) ---
    const int fq = tid & 63;
    const float4 s4 = ((const float4*)sA)[b * 64 + fq];
    const float4 c4 = ((const float4*)cA)[b * 64 + fq];
    const float4 g4 = gamma[fq];
    const float4 t4 = beta[fq];

    const size_t base = (size_t)blk * 16384 + tid;   // float4 units
    const float4* __restrict__ xp = (const float4*)x + base;
    vfloat4* __restrict__ op = (vfloat4*)(out + base);

    #pragma unroll 4
    for (int k = 0; k < 64; ++k) {
        float4 v = xp[k * 256];
        vfloat4 o;
        o.x = fmaf(g4.x, fast_tanh(fmaf(v.x, s4.x, c4.x)), t4.x);
        o.y = fmaf(g4.y, fast_tanh(fmaf(v.y, s4.y, c4.y)), t4.y);
        o.z = fmaf(g4.z, fast_tanh(fmaf(v.z, s4.z, c4.z)), t4.z);
        o.w = fmaf(g4.w, fast_tanh(fmaf(v.w, s4.w, c4.w)), t4.w);
        __builtin_nontemporal_store(o, &op[k * 256]);
    }
}

extern "C" void kernel_launch(void* const* d_in, const int* in_sizes, int n_in,
                              void* d_out, int out_size, void* d_ws, size_t ws_size,
                              hipStream_t stream) {
    const float* x     = (const float*)d_in[0];
    const float* gamma = (const float*)d_in[1];
    const float* beta  = (const float*)d_in[2];
    const float* W1    = (const float*)d_in[3];
    const float* b1    = (const float*)d_in[4];
    const float* W2    = (const float*)d_in[5];
    const float* b2    = (const float*)d_in[6];
    float* out = (float*)d_out;

    float* ws      = (float*)d_ws;
    float* partial = ws;                                   // 1024*512 f = 2 MB
    float* sA      = ws + (size_t)NWG * 2 * NF;            // 64 KB
    float* cA      = sA + NB * NF;                         // 64 KB
    int*   cnt     = (int*)(cA + NB * NF);                 // 64 ints
    int*   flag    = cnt + NB;                             // 64 ints

    // zero cnt+flag each call (graph-capturable stream op)
    hipMemsetAsync(cnt, 0, 2 * NB * sizeof(int), stream);

    k_fused<<<NWG, 256, 0, stream>>>(x, W1, b1, W2, b2,
                                     (const float4*)gamma, (const float4*)beta,
                                     partial, sA, cA, cnt, flag,
                                     (float4*)out);
}

// Round 7
// 249.570 us; speedup vs baseline: 6.8092x; 6.8092x over previous
//
#include <hip/hip_runtime.h>

#define NF 256        // features
#define NT 4096       // time steps
#define NB 64         // batch
#define CHUNKS 16     // time chunks per batch
#define TPC (NT / CHUNKS)   // 256 rows per chunk
#define NWG (NB * CHUNKS)   // 1024 blocks
#define EPS 1e-5f

typedef float vfloat4 __attribute__((ext_vector_type(4)));

__device__ __forceinline__ float fast_tanh(float v) {
    float e = __expf(2.0f * v);                        // inf/0 endpoints -> +-1
    return 1.0f - 2.0f * __builtin_amdgcn_rcpf(e + 1.0f);
}

// ---------------------------------------------------------------------------
// One persistent kernel: reduce own slice -> last-arriver per batch does
// stats+MLP -> all blocks spin on flag -> apply own slice.
// Memory-order discipline (the R6 lesson): NO acquire in the poll loop —
// relaxed agent-scope polls (coherence-point reads, no L2 invalidate),
// one acquire after exit. One ACQ_REL RMW replaces threadfence pairs.
// ---------------------------------------------------------------------------
__global__ __launch_bounds__(256, 4) void k_fused(
    const float* __restrict__ x,
    const float* __restrict__ W1, const float* __restrict__ b1,
    const float* __restrict__ W2, const float* __restrict__ b2,
    const float4* __restrict__ gamma, const float4* __restrict__ beta,
    float* __restrict__ partial, float* __restrict__ sA, float* __restrict__ cA,
    int* __restrict__ cnt, int* __restrict__ flag,
    float4* __restrict__ out)
{
    const int blk = blockIdx.x;
    const int b   = blk >> 4;            // batch
    const int c   = blk & 15;            // chunk
    const int tid = threadIdx.x;
    const int q   = tid & 63;            // float4 slot within a feature row
    const int g   = tid >> 6;            // row group 0..3

    // ---- phase 1: partial sum / sumsq over this chunk's 256 rows ----------
    const float4* __restrict__ xrow =
        (const float4*)(x + ((size_t)b * NT + (size_t)c * TPC) * NF);

    float4 s  = {0.f, 0.f, 0.f, 0.f};
    float4 ss = {0.f, 0.f, 0.f, 0.f};
    #pragma unroll 8
    for (int t = g; t < TPC; t += 4) {
        float4 v = xrow[t * (NF / 4) + q];
        s.x += v.x; s.y += v.y; s.z += v.z; s.w += v.w;
        ss.x = fmaf(v.x, v.x, ss.x);
        ss.y = fmaf(v.y, v.y, ss.y);
        ss.z = fmaf(v.z, v.z, ss.z);
        ss.w = fmaf(v.w, v.w, ss.w);
    }

    __shared__ float4 smS[4][64];
    __shared__ float4 smQ[4][64];
    smS[g][q] = s;
    smQ[g][q] = ss;
    __syncthreads();

    const float* sS = (const float*)smS;
    const float* sQ = (const float*)smQ;
    float sum = sS[0 * NF + tid] + sS[1 * NF + tid] + sS[2 * NF + tid] + sS[3 * NF + tid];
    float sq  = sQ[0 * NF + tid] + sQ[1 * NF + tid] + sQ[2 * NF + tid] + sQ[3 * NF + tid];

    float* p = partial + (size_t)blk * 2 * NF;
    p[tid]      = sum;
    p[NF + tid] = sq;
    __syncthreads();                     // all partial stores issued

    __shared__ int isLast;
    if (tid == 0) {
        // release: writes partials back; acquire: fresh view if we're last
        int old = __hip_atomic_fetch_add(&cnt[b], 1, __ATOMIC_ACQ_REL,
                                         __HIP_MEMORY_SCOPE_AGENT);
        isLast = (old == CHUNKS - 1);
    }
    __syncthreads();

    // ---- phase 2 (one block per batch): stats + MLP + fold constants ------
    if (isLast) {
        const int f = tid;
        float tsum = 0.f, tsq = 0.f;
        #pragma unroll
        for (int cc = 0; cc < CHUNKS; ++cc) {
            const float* pp = partial + (size_t)(b * CHUNKS + cc) * 2 * NF;
            tsum += pp[f];
            tsq  += pp[NF + f];
        }
        const float mean = tsum * (1.0f / NT);
        float var = fmaxf(tsq * (1.0f / NT) - mean * mean, 0.0f);
        const float stdv = sqrtf(var + EPS);

        __shared__ float stats[2 * NF];
        __shared__ float h[NF];
        stats[f]      = mean;
        stats[NF + f] = stdv;
        __syncthreads();

        float acc = b1[f];
        const float* w1r = W1 + (size_t)f * (2 * NF);
        #pragma unroll 8
        for (int k = 0; k < 2 * NF; ++k) acc = fmaf(stats[k], w1r[k], acc);
        h[f] = fmaxf(acc, 0.0f);
        __syncthreads();

        float acc2 = b2[f];
        const float* w2r = W2 + (size_t)f * NF;
        #pragma unroll 8
        for (int k = 0; k < NF; ++k) acc2 = fmaf(h[k], w2r[k], acc2);
        const float alpha = 1.0f / (1.0f + __expf(-acc2));

        const float sv = alpha / stdv;
        sA[b * NF + f] = sv;             // scale
        cA[b * NF + f] = -mean * sv;     // offset
        __syncthreads();                 // all sA/cA stores issued
        if (tid == 0)                    // release store writes them back
            __hip_atomic_store(&flag[b], 1, __ATOMIC_RELEASE,
                               __HIP_MEMORY_SCOPE_AGENT);
    }

    // ---- wait for this batch's constants: RELAXED polls, acquire ONCE -----
    if (tid == 0) {
        while (__hip_atomic_load(&flag[b], __ATOMIC_RELAXED,
                                 __HIP_MEMORY_SCOPE_AGENT) == 0) {
            __builtin_amdgcn_s_sleep(8);
        }
        (void)__hip_atomic_load(&flag[b], __ATOMIC_ACQUIRE,
                                __HIP_MEMORY_SCOPE_AGENT);  // one L2 refresh
    }
    __syncthreads();

    // ---- phase 3: apply on own slice --------------------------------------
    const int fq = tid & 63;
    const float4 s4 = ((const float4*)sA)[b * 64 + fq];
    const float4 c4 = ((const float4*)cA)[b * 64 + fq];
    const float4 g4 = gamma[fq];
    const float4 t4 = beta[fq];

    const size_t base = (size_t)blk * 16384 + tid;   // float4 units
    const float4* __restrict__ xp = (const float4*)x + base;
    vfloat4* __restrict__ op = (vfloat4*)(out + base);

    #pragma unroll 4
    for (int k = 0; k < 64; ++k) {
        float4 v = xp[k * 256];
        vfloat4 o;
        o.x = fmaf(g4.x, fast_tanh(fmaf(v.x, s4.x, c4.x)), t4.x);
        o.y = fmaf(g4.y, fast_tanh(fmaf(v.y, s4.y, c4.y)), t4.y);
        o.z = fmaf(g4.z, fast_tanh(fmaf(v.z, s4.z, c4.z)), t4.z);
        o.w = fmaf(g4.w, fast_tanh(fmaf(v.w, s4.w, c4.w)), t4.w);
        __builtin_nontemporal_store(o, &op[k * 256]);
    }
}

extern "C" void kernel_launch(void* const* d_in, const int* in_sizes, int n_in,
                              void* d_out, int out_size, void* d_ws, size_t ws_size,
                              hipStream_t stream) {
    const float* x     = (const float*)d_in[0];
    const float* gamma = (const float*)d_in[1];
    const float* beta  = (const float*)d_in[2];
    const float* W1    = (const float*)d_in[3];
    const float* b1    = (const float*)d_in[4];
    const float* W2    = (const float*)d_in[5];
    const float* b2    = (const float*)d_in[6];
    float* out = (float*)d_out;

    float* ws      = (float*)d_ws;
    float* partial = ws;                                   // 1024*512 f = 2 MB
    float* sA      = ws + (size_t)NWG * 2 * NF;            // 64 KB
    float* cA      = sA + NB * NF;                         // 64 KB
    int*   cnt     = (int*)(cA + NB * NF);                 // 64 ints
    int*   flag    = cnt + NB;                             // 64 ints

    // zero cnt+flag each call (graph-capturable stream op)
    hipMemsetAsync(cnt, 0, 2 * NB * sizeof(int), stream);

    k_fused<<<NWG, 256, 0, stream>>>(x, W1, b1, W2, b2,
                                     (const float4*)gamma, (const float4*)beta,
                                     partial, sA, cA, cnt, flag,
                                     (float4*)out);
}

// Round 8
// 248.853 us; speedup vs baseline: 6.8288x; 1.0029x over previous
//
#include <hip/hip_runtime.h>

#define NF 256        // features
#define NT 4096       // time steps
#define NB 64         // batch
#define CHUNKS 16     // time chunks per batch
#define TPC (NT / CHUNKS)   // 256 rows per chunk
#define NWG (NB * CHUNKS)   // 1024 blocks
#define EPS 1e-5f
#define PAD 32        // ints per control slot -> 128 B, one cache line apart

typedef float vfloat4 __attribute__((ext_vector_type(4)));

__device__ __forceinline__ float fast_tanh(float v) {
    float e = __expf(2.0f * v);                        // inf/0 endpoints -> +-1
    return 1.0f - 2.0f * __builtin_amdgcn_rcpf(e + 1.0f);
}

__device__ __forceinline__ float relaxed_load_f32(const float* p) {
    unsigned u = __hip_atomic_load((unsigned*)p, __ATOMIC_RELAXED,
                                   __HIP_MEMORY_SCOPE_AGENT);
    return __uint_as_float(u);
}

// ---------------------------------------------------------------------------
// Fused persistent kernel, fabric-silent sync (R7 lesson):
//  - control words padded to 128 B (16 pollers/line max)
//  - polls every ~3.4 us (s_sleep(127)), relaxed scope (no L2 invalidate)
//  - release-only RMW; acquire only in the 64 isLast blocks
//  - consumers read sA/cA via relaxed agent loads (coherence-point reads),
//    so non-last blocks execute ZERO cache-invalidating ops.
// ---------------------------------------------------------------------------
__global__ __launch_bounds__(256, 4) void k_fused(
    const float* __restrict__ x,
    const float* __restrict__ W1, const float* __restrict__ b1,
    const float* __restrict__ W2, const float* __restrict__ b2,
    const float4* __restrict__ gamma, const float4* __restrict__ beta,
    float* __restrict__ partial, float* __restrict__ sA, float* __restrict__ cA,
    int* __restrict__ cnt, int* __restrict__ flag,
    float4* __restrict__ out)
{
    const int blk = blockIdx.x;
    const int b   = blk >> 4;            // batch
    const int c   = blk & 15;            // chunk
    const int tid = threadIdx.x;
    const int q   = tid & 63;            // float4 slot within a feature row
    const int g   = tid >> 6;            // row group 0..3

    // ---- phase 1: partial sum / sumsq over this chunk's 256 rows ----------
    const float4* __restrict__ xrow =
        (const float4*)(x + ((size_t)b * NT + (size_t)c * TPC) * NF);

    float4 s  = {0.f, 0.f, 0.f, 0.f};
    float4 ss = {0.f, 0.f, 0.f, 0.f};
    #pragma unroll 8
    for (int t = g; t < TPC; t += 4) {
        float4 v = xrow[t * (NF / 4) + q];
        s.x += v.x; s.y += v.y; s.z += v.z; s.w += v.w;
        ss.x = fmaf(v.x, v.x, ss.x);
        ss.y = fmaf(v.y, v.y, ss.y);
        ss.z = fmaf(v.z, v.z, ss.z);
        ss.w = fmaf(v.w, v.w, ss.w);
    }

    __shared__ float4 smS[4][64];
    __shared__ float4 smQ[4][64];
    smS[g][q] = s;
    smQ[g][q] = ss;
    __syncthreads();

    const float* sS = (const float*)smS;
    const float* sQ = (const float*)smQ;
    float sum = sS[0 * NF + tid] + sS[1 * NF + tid] + sS[2 * NF + tid] + sS[3 * NF + tid];
    float sq  = sQ[0 * NF + tid] + sQ[1 * NF + tid] + sQ[2 * NF + tid] + sQ[3 * NF + tid];

    float* p = partial + (size_t)blk * 2 * NF;
    p[tid]      = sum;
    p[NF + tid] = sq;
    __syncthreads();                     // all partial stores issued

    __shared__ int isLast;
    if (tid == 0) {
        // RELEASE-only: write back our partials; no invalidate here.
        int old = __hip_atomic_fetch_add(&cnt[b * PAD], 1, __ATOMIC_RELEASE,
                                         __HIP_MEMORY_SCOPE_AGENT);
        isLast = (old == CHUNKS - 1);
    }
    __syncthreads();

    // ---- phase 2 (one block per batch): stats + MLP + fold constants ------
    if (isLast) {
        if (tid == 0)                    // single acquire for partial reads
            (void)__hip_atomic_load(&cnt[b * PAD], __ATOMIC_ACQUIRE,
                                    __HIP_MEMORY_SCOPE_AGENT);
        __syncthreads();

        const int f = tid;
        float tsum = 0.f, tsq = 0.f;
        #pragma unroll
        for (int cc = 0; cc < CHUNKS; ++cc) {
            const float* pp = partial + (size_t)(b * CHUNKS + cc) * 2 * NF;
            tsum += pp[f];
            tsq  += pp[NF + f];
        }
        const float mean = tsum * (1.0f / NT);
        float var = fmaxf(tsq * (1.0f / NT) - mean * mean, 0.0f);
        const float stdv = sqrtf(var + EPS);

        __shared__ float stats[2 * NF];
        __shared__ float h[NF];
        stats[f]      = mean;
        stats[NF + f] = stdv;
        __syncthreads();

        float acc = b1[f];
        const float* w1r = W1 + (size_t)f * (2 * NF);
        #pragma unroll 8
        for (int k = 0; k < 2 * NF; ++k) acc = fmaf(stats[k], w1r[k], acc);
        h[f] = fmaxf(acc, 0.0f);
        __syncthreads();

        float acc2 = b2[f];
        const float* w2r = W2 + (size_t)f * NF;
        #pragma unroll 8
        for (int k = 0; k < NF; ++k) acc2 = fmaf(h[k], w2r[k], acc2);
        const float alpha = 1.0f / (1.0f + __expf(-acc2));

        const float sv = alpha / stdv;
        sA[b * NF + f] = sv;             // scale
        cA[b * NF + f] = -mean * sv;     // offset
        __syncthreads();                 // all sA/cA stores issued
        if (tid == 0)                    // release: write them back, set flag
            __hip_atomic_store(&flag[b * PAD], 1, __ATOMIC_RELEASE,
                               __HIP_MEMORY_SCOPE_AGENT);
    }

    // ---- wait: slow relaxed polls on a private line (no invalidates) ------
    if (tid == 0) {
        while (__hip_atomic_load(&flag[b * PAD], __ATOMIC_RELAXED,
                                 __HIP_MEMORY_SCOPE_AGENT) == 0) {
            __builtin_amdgcn_s_sleep(127);       // ~3.4 us between polls
        }
    }
    __syncthreads();   // hw+compiler barrier: loads below stay below

    // ---- pull folded constants via coherence-point reads into LDS ---------
    __shared__ float sRow[NF];
    __shared__ float cRow[NF];
    sRow[tid] = relaxed_load_f32(sA + b * NF + tid);
    cRow[tid] = relaxed_load_f32(cA + b * NF + tid);
    __syncthreads();

    // ---- phase 3: apply on own slice ---------------------------------------
    const int fq = tid & 63;
    const float4 s4 = ((const float4*)sRow)[fq];
    const float4 c4 = ((const float4*)cRow)[fq];
    const float4 g4 = gamma[fq];
    const float4 t4 = beta[fq];

    const size_t base = (size_t)blk * 16384 + tid;   // float4 units
    const float4* __restrict__ xp = (const float4*)x + base;
    vfloat4* __restrict__ op = (vfloat4*)(out + base);

    #pragma unroll 4
    for (int k = 0; k < 64; ++k) {
        float4 v = xp[k * 256];
        vfloat4 o;
        o.x = fmaf(g4.x, fast_tanh(fmaf(v.x, s4.x, c4.x)), t4.x);
        o.y = fmaf(g4.y, fast_tanh(fmaf(v.y, s4.y, c4.y)), t4.y);
        o.z = fmaf(g4.z, fast_tanh(fmaf(v.z, s4.z, c4.z)), t4.z);
        o.w = fmaf(g4.w, fast_tanh(fmaf(v.w, s4.w, c4.w)), t4.w);
        __builtin_nontemporal_store(o, &op[k * 256]);
    }
}

extern "C" void kernel_launch(void* const* d_in, const int* in_sizes, int n_in,
                              void* d_out, int out_size, void* d_ws, size_t ws_size,
                              hipStream_t stream) {
    const float* x     = (const float*)d_in[0];
    const float* gamma = (const float*)d_in[1];
    const float* beta  = (const float*)d_in[2];
    const float* W1    = (const float*)d_in[3];
    const float* b1    = (const float*)d_in[4];
    const float* W2    = (const float*)d_in[5];
    const float* b2    = (const float*)d_in[6];
    float* out = (float*)d_out;

    float* ws      = (float*)d_ws;
    float* partial = ws;                                   // 1024*512 f = 2 MB
    float* sA      = ws + (size_t)NWG * 2 * NF;            // 64 KB
    float* cA      = sA + NB * NF;                         // 64 KB
    int*   cnt     = (int*)(cA + NB * NF);                 // 64*32 ints = 8 KB
    int*   flag    = cnt + NB * PAD;                       // 64*32 ints = 8 KB

    // zero cnt+flag each call (graph-capturable stream op)
    hipMemsetAsync(cnt, 0, 2 * NB * PAD * sizeof(int), stream);

    k_fused<<<NWG, 256, 0, stream>>>(x, W1, b1, W2, b2,
                                     (const float4*)gamma, (const float4*)beta,
                                     partial, sA, cA, cnt, flag,
                                     (float4*)out);
}